// Round 5
// baseline (372.729 us; speedup 1.0000x reference)
//
#include <hip/hip_runtime.h>

// Segment-average pooling, sort-based.
//   input  [B=8, C=128, N=65536] fp32, labels [B, N] int32 in [0, 1024)
//   out    [B, S=1024, C=128] fp32 segment means
//
// R5 vs R4: the reduce loop read buf[~4s+i] -> bank-quad (4s+i) mod 8 ->
// ~32-lane quad aliasing on every ds_read_b128 (~4x baseline, ~10k cyc/tile
// — the whole gap to the HBM floor). Fix: swizzled physical slot
// psi(j) = j + (j>>3) (injective, spreads mod-8 residues over all 8 quads),
// plus pair-unrolled reduce (2 independent ds_read_b128 per iteration).

#define BB 8
#define CC 128
#define NPIX 65536      // 256*256
#define SS 1024
#define TILE 4096
#define NTILES (NPIX / TILE)   // 16
#define THREADS 1024
#define BUFSZ (TILE + TILE / 8)   // 4608 float4 = 72 KiB, swizzle range

#define POS_ELEMS (BB * NPIX)           // u16 sorted position within tile
#define OFF_ELEMS (BB * NTILES * SS)    // u16 exclusive offsets per tile

__device__ __forceinline__ int swz(int j) { return j + (j >> 3); }

// Workgroup barrier that orders LDS only — does NOT drain vmcnt, so global
// loads issued before it stay in flight. All waves reach it uniformly.
__device__ __forceinline__ void lds_barrier() {
  asm volatile("s_waitcnt lgkmcnt(0)\n\ts_barrier" ::: "memory");
}

// ---------------- Kernel A: per-tile counting sort metadata ----------------
__global__ __launch_bounds__(THREADS, 1) void sort_kernel(
    const int* __restrict__ seg, unsigned short* __restrict__ pos,
    unsigned short* __restrict__ tileoff) {
  __shared__ unsigned int hist[SS];
  __shared__ unsigned int wsum[16];
  const int b   = blockIdx.x / NTILES;
  const int t   = blockIdx.x % NTILES;
  const int tid = threadIdx.x;

  hist[tid] = 0u;   // THREADS == SS
  __syncthreads();

  const int base = b * NPIX + t * TILE;
  const int4 lab = reinterpret_cast<const int4*>(seg + base)[tid];
  const unsigned int r0 = atomicAdd(&hist[lab.x], 1u);
  const unsigned int r1 = atomicAdd(&hist[lab.y], 1u);
  const unsigned int r2 = atomicAdd(&hist[lab.z], 1u);
  const unsigned int r3 = atomicAdd(&hist[lab.w], 1u);
  __syncthreads();

  const unsigned int cnt = hist[tid];
  // inclusive wave-scan (64 lanes, shuffle, no barriers)
  unsigned int v = cnt;
  #pragma unroll
  for (int off = 1; off < 64; off <<= 1) {
    const unsigned int u = __shfl_up(v, off);
    if ((tid & 63) >= off) v += u;
  }
  const int w = tid >> 6;
  if ((tid & 63) == 63) wsum[w] = v;
  __syncthreads();
  if (tid < 16) {   // scan the 16 wave totals (lanes 0..15 of wave 0)
    unsigned int x = wsum[tid];
    #pragma unroll
    for (int off = 1; off < 16; off <<= 1) {
      const unsigned int u = __shfl_up(x, off);
      if (tid >= off) x += u;
    }
    wsum[tid] = x;  // inclusive
  }
  __syncthreads();
  const unsigned int woff = (w == 0) ? 0u : wsum[w - 1];
  const unsigned int excl = woff + v - cnt;   // exclusive offset of segment tid
  tileoff[(b * NTILES + t) * SS + tid] = (unsigned short)excl;
  hist[tid] = excl;
  __syncthreads();

  ushort4 p4;
  p4.x = (unsigned short)(hist[lab.x] + r0);
  p4.y = (unsigned short)(hist[lab.y] + r1);
  p4.z = (unsigned short)(hist[lab.z] + r2);
  p4.w = (unsigned short)(hist[lab.w] + r3);
  reinterpret_cast<ushort4*>(pos + base)[tid] = p4;
}

// ---------------- Kernel B: scatter to sorted LDS, ordered reduce ----------
__global__ __launch_bounds__(THREADS, 1) void aggr_kernel(
    const float* __restrict__ inp, const unsigned short* __restrict__ pos,
    const unsigned short* __restrict__ tileoff, float* __restrict__ out) {
  __shared__ float4 buf[BUFSZ];             // 72 KiB, swizzled sorted vectors
  __shared__ unsigned short offl[SS + 2];   // per-tile exclusive offsets

  const int b   = blockIdx.x >> 5;          // / (CC/4)
  const int c0  = (blockIdx.x & 31) << 2;   // channel chunk base
  const int tid = threadIdx.x;              // == segment id for the reduce

  const float4* __restrict__ pl0 =
      reinterpret_cast<const float4*>(inp + ((size_t)b * CC + c0) * NPIX);
  const ushort4* __restrict__ pos4 =
      reinterpret_cast<const ushort4*>(pos + (size_t)b * NPIX);
  const int Q = NPIX / 4;                   // float4 per channel plane

  float a0 = 0.f, a1 = 0.f, a2 = 0.f, a3 = 0.f;
  int cnt = 0;

  // preload tile 0 into registers
  float4 cv0 = pl0[tid], cv1 = pl0[tid + Q];
  float4 cv2 = pl0[tid + 2 * Q], cv3 = pl0[tid + 3 * Q];
  ushort4 cp4 = pos4[tid];
  unsigned short coff = tileoff[(b * NTILES + 0) * SS + tid];

  for (int t = 0; t < NTILES; ++t) {
    lds_barrier();              // reduce(t-1) readers done; loads stay in flight
    if (tid == 0) offl[SS] = (unsigned short)TILE;
    offl[tid] = coff;
    // transpose 4x4 in regs -> pixel-vectors, scatter to swizzled sorted slots
    buf[swz(cp4.x)] = make_float4(cv0.x, cv1.x, cv2.x, cv3.x);
    buf[swz(cp4.y)] = make_float4(cv0.y, cv1.y, cv2.y, cv3.y);
    buf[swz(cp4.z)] = make_float4(cv0.z, cv1.z, cv2.z, cv3.z);
    buf[swz(cp4.w)] = make_float4(cv0.w, cv1.w, cv2.w, cv3.w);

    // prefetch tile t+1 (issued now; waited at next scatter's register uses)
    const int tn = (t + 1 < NTILES) ? t + 1 : t;
    const int pn = tn * (TILE / 4) + tid;
    const float4 nv0 = pl0[pn], nv1 = pl0[pn + Q];
    const float4 nv2 = pl0[pn + 2 * Q], nv3 = pl0[pn + 3 * Q];
    const ushort4 np4 = pos4[pn];
    const unsigned short noff = tileoff[(b * NTILES + tn) * SS + tid];

    lds_barrier();              // scatter(t) visible to all waves
    const int beg = offl[tid];
    const int end = offl[tid + 1];
    cnt += end - beg;
    int j = beg;
    for (; j + 2 <= end; j += 2) {   // contiguous run, single owner, 2x ILP
      const float4 u = buf[swz(j)];
      const float4 v = buf[swz(j + 1)];
      a0 += u.x; a1 += u.y; a2 += u.z; a3 += u.w;
      a0 += v.x; a1 += v.y; a2 += v.z; a3 += v.w;
    }
    if (j < end) {
      const float4 u = buf[swz(j)];
      a0 += u.x; a1 += u.y; a2 += u.z; a3 += u.w;
    }

    cv0 = nv0; cv1 = nv1; cv2 = nv2; cv3 = nv3; cp4 = np4; coff = noff;
  }

  const float inv = 1.0f / (float)max(cnt, 1);
  reinterpret_cast<float4*>(out + ((size_t)(b * SS + tid)) * CC + c0)[0] =
      make_float4(a0 * inv, a1 * inv, a2 * inv, a3 * inv);
}

// ---------------- Fallback (R2): LDS-atomic version, needs no ws -----------
__global__ __launch_bounds__(THREADS, 1) void seg_avg_kernel(
    const float* __restrict__ inp, const int* __restrict__ seg,
    float* __restrict__ out) {
  __shared__ float acc[SS * 5];
  const int b   = blockIdx.x >> 5;
  const int c0  = (blockIdx.x & 31) << 2;
  const int tid = threadIdx.x;
  for (int i = tid; i < SS * 5; i += THREADS) acc[i] = 0.0f;
  __syncthreads();
  const float4* __restrict__ p0 =
      reinterpret_cast<const float4*>(inp + ((size_t)b * CC + c0) * NPIX);
  const int4* __restrict__ lab = reinterpret_cast<const int4*>(seg + (size_t)b * NPIX);
  const int Q = NPIX / 4;
  int* iacc = reinterpret_cast<int*>(acc);
  for (int i = 0; i < NPIX / (4 * THREADS); ++i) {
    const int p = i * THREADS + tid;
    const int4 s4 = lab[p];
    const float4 v0 = p0[p], v1 = p0[p + Q], v2 = p0[p + 2 * Q], v3 = p0[p + 3 * Q];
    const int a0 = s4.x * 5, a1 = s4.y * 5, a2 = s4.z * 5, a3 = s4.w * 5;
    unsafeAtomicAdd(&acc[a0 + 0], v0.x); unsafeAtomicAdd(&acc[a0 + 1], v1.x);
    unsafeAtomicAdd(&acc[a0 + 2], v2.x); unsafeAtomicAdd(&acc[a0 + 3], v3.x);
    atomicAdd(&iacc[a0 + 4], 1);
    unsafeAtomicAdd(&acc[a1 + 0], v0.y); unsafeAtomicAdd(&acc[a1 + 1], v1.y);
    unsafeAtomicAdd(&acc[a1 + 2], v2.y); unsafeAtomicAdd(&acc[a1 + 3], v3.y);
    atomicAdd(&iacc[a1 + 4], 1);
    unsafeAtomicAdd(&acc[a2 + 0], v0.z); unsafeAtomicAdd(&acc[a2 + 1], v1.z);
    unsafeAtomicAdd(&acc[a2 + 2], v2.z); unsafeAtomicAdd(&acc[a2 + 3], v3.z);
    atomicAdd(&iacc[a2 + 4], 1);
    unsafeAtomicAdd(&acc[a3 + 0], v0.w); unsafeAtomicAdd(&acc[a3 + 1], v1.w);
    unsafeAtomicAdd(&acc[a3 + 2], v2.w); unsafeAtomicAdd(&acc[a3 + 3], v3.w);
    atomicAdd(&iacc[a3 + 4], 1);
  }
  __syncthreads();
  for (int i = tid; i < SS * 4; i += THREADS) {
    const int s = i >> 2, c = i & 3;
    const float cntf = (float)iacc[s * 5 + 4];
    out[((size_t)(b * SS + s)) * CC + c0 + c] = acc[s * 5 + c] / fmaxf(cntf, 1.0f);
  }
}

extern "C" void kernel_launch(void* const* d_in, const int* in_sizes, int n_in,
                              void* d_out, int out_size, void* d_ws, size_t ws_size,
                              hipStream_t stream) {
  const float* inp = (const float*)d_in[0];
  const int*   seg = (const int*)d_in[1];
  float*       out = (float*)d_out;

  const size_t need = (size_t)POS_ELEMS * 2 + (size_t)OFF_ELEMS * 2;  // 1.25 MiB
  if (ws_size >= need) {
    unsigned short* pos  = (unsigned short*)d_ws;
    unsigned short* toff = pos + POS_ELEMS;
    sort_kernel<<<BB * NTILES, THREADS, 0, stream>>>(seg, pos, toff);
    aggr_kernel<<<BB * (CC / 4), THREADS, 0, stream>>>(inp, pos, toff, out);
  } else {
    seg_avg_kernel<<<BB * (CC / 4), THREADS, 0, stream>>>(inp, seg, out);
  }
}

// Round 6
// 369.595 us; speedup vs baseline: 1.0085x; 1.0085x over previous
//
#include <hip/hip_runtime.h>

// Segment-average pooling, sort-based, 2-blocks-per-CU pipelined.
//   input  [B=8, C=128, N=65536] fp32, labels [B, N] int32 in [0, 1024)
//   out    [B, S=1024, C=128] fp32 segment means
//
// R6 vs R5: R4 (barrier type) and R5 (reduce swizzle) were both FLAT ->
// the invariant is 1 block/CU phase serialization: HBM idles during every
// scatter/reduce/barrier phase. Fix at the scheduler level: 2-channel
// chunks -> 512 blocks, buf = float2[5120] (40 KiB) + launch_bounds cap
// VGPR<=64 -> 2 co-resident blocks per CU; block A's load burst fills
// block B's LDS-phase gaps. Tile-order parity offset desyncs the pair.

#define BB 8
#define CC 128
#define NPIX 65536      // 256*256
#define SS 1024
#define TILE 4096
#define NTILES (NPIX / TILE)   // 16
#define THREADS 1024
#define BUFSZ2 (TILE + TILE / 4)   // 5120 float2 = 40 KiB (swizzle range)

#define POS_ELEMS (BB * NPIX)           // u16 sorted position within tile
#define OFF_ELEMS (BB * NTILES * SS)    // u16 exclusive offsets per tile

// swizzle: psi(e) = e + (e>>2); injective, reduce-run bank stride 10 mod 32
// -> 16 distinct banks over 64 lanes (4-way, ~1.58x — near-free).
__device__ __forceinline__ int swz2(int e) { return e + (e >> 2); }

// ---------------- Kernel A: per-tile counting sort metadata ----------------
__global__ __launch_bounds__(THREADS, 1) void sort_kernel(
    const int* __restrict__ seg, unsigned short* __restrict__ pos,
    unsigned short* __restrict__ tileoff) {
  __shared__ unsigned int hist[SS];
  __shared__ unsigned int wsum[16];
  const int b   = blockIdx.x / NTILES;
  const int t   = blockIdx.x % NTILES;
  const int tid = threadIdx.x;

  hist[tid] = 0u;   // THREADS == SS
  __syncthreads();

  const int base = b * NPIX + t * TILE;
  const int4 lab = reinterpret_cast<const int4*>(seg + base)[tid];
  const unsigned int r0 = atomicAdd(&hist[lab.x], 1u);
  const unsigned int r1 = atomicAdd(&hist[lab.y], 1u);
  const unsigned int r2 = atomicAdd(&hist[lab.z], 1u);
  const unsigned int r3 = atomicAdd(&hist[lab.w], 1u);
  __syncthreads();

  const unsigned int cnt = hist[tid];
  // inclusive wave-scan (64 lanes, shuffle, no barriers)
  unsigned int v = cnt;
  #pragma unroll
  for (int off = 1; off < 64; off <<= 1) {
    const unsigned int u = __shfl_up(v, off);
    if ((tid & 63) >= off) v += u;
  }
  const int w = tid >> 6;
  if ((tid & 63) == 63) wsum[w] = v;
  __syncthreads();
  if (tid < 16) {   // scan the 16 wave totals (lanes 0..15 of wave 0)
    unsigned int x = wsum[tid];
    #pragma unroll
    for (int off = 1; off < 16; off <<= 1) {
      const unsigned int u = __shfl_up(x, off);
      if (tid >= off) x += u;
    }
    wsum[tid] = x;  // inclusive
  }
  __syncthreads();
  const unsigned int woff = (w == 0) ? 0u : wsum[w - 1];
  const unsigned int excl = woff + v - cnt;   // exclusive offset of segment tid
  tileoff[(b * NTILES + t) * SS + tid] = (unsigned short)excl;
  hist[tid] = excl;
  __syncthreads();

  ushort4 p4;
  p4.x = (unsigned short)(hist[lab.x] + r0);
  p4.y = (unsigned short)(hist[lab.y] + r1);
  p4.z = (unsigned short)(hist[lab.z] + r2);
  p4.w = (unsigned short)(hist[lab.w] + r3);
  reinterpret_cast<ushort4*>(pos + base)[tid] = p4;
}

// ---------------- Kernel B: scatter to sorted LDS, ordered reduce ----------
// 512 blocks = (image b, channel pair c0). 2 blocks/CU for phase overlap.
__global__ __launch_bounds__(THREADS, 8) void aggr_kernel(
    const float* __restrict__ inp, const unsigned short* __restrict__ pos,
    const unsigned short* __restrict__ tileoff, float* __restrict__ out) {
  __shared__ float2 buf[BUFSZ2];            // 40 KiB swizzled sorted vectors
  __shared__ unsigned short offl[SS + 2];   // per-tile exclusive offsets

  const int b   = blockIdx.x >> 6;          // / (CC/2)
  const int c0  = (blockIdx.x & 63) << 1;   // channel pair base
  const int tid = threadIdx.x;              // == segment id for the reduce
  const int tphase = (blockIdx.x & 1) << 3; // desync co-resident pair by 8 tiles

  const float4* __restrict__ pl0 =
      reinterpret_cast<const float4*>(inp + ((size_t)b * CC + c0) * NPIX);
  const ushort4* __restrict__ pos4 =
      reinterpret_cast<const ushort4*>(pos + (size_t)b * NPIX);
  const int Q = NPIX / 4;                   // float4 per channel plane

  float a0 = 0.f, a1 = 0.f;
  int cnt = 0;

  // preload first tile into registers
  int t0 = tphase;
  int p0i = t0 * (TILE / 4) + tid;
  float4 cv0 = pl0[p0i], cv1 = pl0[p0i + Q];
  ushort4 cp4 = pos4[p0i];
  unsigned short coff = tileoff[(b * NTILES + t0) * SS + tid];

  for (int k = 0; k < NTILES; ++k) {
    __syncthreads();            // reduce(prev) readers done before overwrite
    if (tid == 0) offl[SS] = (unsigned short)TILE;
    offl[tid] = coff;
    // transpose in regs -> pixel float2 (ch c0, c0+1), scatter to swizzled slots
    buf[swz2(cp4.x)] = make_float2(cv0.x, cv1.x);
    buf[swz2(cp4.y)] = make_float2(cv0.y, cv1.y);
    buf[swz2(cp4.z)] = make_float2(cv0.z, cv1.z);
    buf[swz2(cp4.w)] = make_float2(cv0.w, cv1.w);

    // prefetch next tile (registers); waited at next scatter's uses
    const int kn = (k + 1 < NTILES) ? k + 1 : k;
    const int tn = (kn + tphase) & (NTILES - 1);
    const int pn = tn * (TILE / 4) + tid;
    const float4 nv0 = pl0[pn], nv1 = pl0[pn + Q];
    const ushort4 np4 = pos4[pn];
    const unsigned short noff = tileoff[(b * NTILES + tn) * SS + tid];

    __syncthreads();            // scatter visible to all waves
    const int beg = offl[tid];
    const int end = offl[tid + 1];
    cnt += end - beg;
    int j = beg;
    for (; j + 2 <= end; j += 2) {   // contiguous run, single owner, 2x ILP
      const float2 u = buf[swz2(j)];
      const float2 v = buf[swz2(j + 1)];
      a0 += u.x + v.x; a1 += u.y + v.y;
    }
    if (j < end) {
      const float2 u = buf[swz2(j)];
      a0 += u.x; a1 += u.y;
    }

    cv0 = nv0; cv1 = nv1; cp4 = np4; coff = noff;
  }

  const float inv = 1.0f / (float)max(cnt, 1);
  reinterpret_cast<float2*>(out + ((size_t)(b * SS + tid)) * CC + c0)[0] =
      make_float2(a0 * inv, a1 * inv);
}

// ---------------- Fallback (R2): LDS-atomic version, needs no ws -----------
__global__ __launch_bounds__(THREADS, 1) void seg_avg_kernel(
    const float* __restrict__ inp, const int* __restrict__ seg,
    float* __restrict__ out) {
  __shared__ float acc[SS * 5];
  const int b   = blockIdx.x >> 5;
  const int c0  = (blockIdx.x & 31) << 2;
  const int tid = threadIdx.x;
  for (int i = tid; i < SS * 5; i += THREADS) acc[i] = 0.0f;
  __syncthreads();
  const float4* __restrict__ p0 =
      reinterpret_cast<const float4*>(inp + ((size_t)b * CC + c0) * NPIX);
  const int4* __restrict__ lab = reinterpret_cast<const int4*>(seg + (size_t)b * NPIX);
  const int Q = NPIX / 4;
  int* iacc = reinterpret_cast<int*>(acc);
  for (int i = 0; i < NPIX / (4 * THREADS); ++i) {
    const int p = i * THREADS + tid;
    const int4 s4 = lab[p];
    const float4 v0 = p0[p], v1 = p0[p + Q], v2 = p0[p + 2 * Q], v3 = p0[p + 3 * Q];
    const int a0 = s4.x * 5, a1 = s4.y * 5, a2 = s4.z * 5, a3 = s4.w * 5;
    unsafeAtomicAdd(&acc[a0 + 0], v0.x); unsafeAtomicAdd(&acc[a0 + 1], v1.x);
    unsafeAtomicAdd(&acc[a0 + 2], v2.x); unsafeAtomicAdd(&acc[a0 + 3], v3.x);
    atomicAdd(&iacc[a0 + 4], 1);
    unsafeAtomicAdd(&acc[a1 + 0], v0.y); unsafeAtomicAdd(&acc[a1 + 1], v1.y);
    unsafeAtomicAdd(&acc[a1 + 2], v2.y); unsafeAtomicAdd(&acc[a1 + 3], v3.y);
    atomicAdd(&iacc[a1 + 4], 1);
    unsafeAtomicAdd(&acc[a2 + 0], v0.z); unsafeAtomicAdd(&acc[a2 + 1], v1.z);
    unsafeAtomicAdd(&acc[a2 + 2], v2.z); unsafeAtomicAdd(&acc[a2 + 3], v3.z);
    atomicAdd(&iacc[a2 + 4], 1);
    unsafeAtomicAdd(&acc[a3 + 0], v0.w); unsafeAtomicAdd(&acc[a3 + 1], v1.w);
    unsafeAtomicAdd(&acc[a3 + 2], v2.w); unsafeAtomicAdd(&acc[a3 + 3], v3.w);
    atomicAdd(&iacc[a3 + 4], 1);
  }
  __syncthreads();
  for (int i = tid; i < SS * 4; i += THREADS) {
    const int s = i >> 2, c = i & 3;
    const float cntf = (float)iacc[s * 5 + 4];
    out[((size_t)(b * SS + s)) * CC + c0 + c] = acc[s * 5 + c] / fmaxf(cntf, 1.0f);
  }
}

extern "C" void kernel_launch(void* const* d_in, const int* in_sizes, int n_in,
                              void* d_out, int out_size, void* d_ws, size_t ws_size,
                              hipStream_t stream) {
  const float* inp = (const float*)d_in[0];
  const int*   seg = (const int*)d_in[1];
  float*       out = (float*)d_out;

  const size_t need = (size_t)POS_ELEMS * 2 + (size_t)OFF_ELEMS * 2;  // 1.25 MiB
  if (ws_size >= need) {
    unsigned short* pos  = (unsigned short*)d_ws;
    unsigned short* toff = pos + POS_ELEMS;
    sort_kernel<<<BB * NTILES, THREADS, 0, stream>>>(seg, pos, toff);
    aggr_kernel<<<BB * (CC / 2), THREADS, 0, stream>>>(inp, pos, toff, out);
  } else {
    seg_avg_kernel<<<BB * (CC / 4), THREADS, 0, stream>>>(inp, seg, out);
  }
}